// Round 1
// baseline (557.210 us; speedup 1.0000x reference)
//
#include <hip/hip_runtime.h>

#define SDIM 16384
#define RANK 64
#define NMID 6

// ---------------------------------------------------------------------------
// Kernel 1: partial V_mid.  grid = NMID*RANK*nchunk blocks, 256 threads.
// Block handles one (k,a) pair and one s-chunk.  Thread layout: 16 float4
// columns x 16 s-rows.  Deterministic (fixed-order LDS reduce, no atomics).
// ---------------------------------------------------------------------------
__global__ __launch_bounds__(256) void k_vmid_partial(
    const float* __restrict__ z, const float* __restrict__ tt_mid,
    float* __restrict__ part, int nchunk) {
  const int idx = blockIdx.x;
  const int c = idx % nchunk;
  const int ka = idx / nchunk;                     // k*64 + a, 0..383
  const int chunk_len = SDIM / nchunk;
  const float* __restrict__ src =
      tt_mid + ((size_t)ka * SDIM + (size_t)c * chunk_len) * RANK;
  const float* __restrict__ zz = z + (size_t)c * chunk_len;

  const int b4 = threadIdx.x & 15;                 // which float4 of the 64 cols
  const int row = threadIdx.x >> 4;                // 0..15

  float4 acc = {0.f, 0.f, 0.f, 0.f};
#pragma unroll 4
  for (int s = row; s < chunk_len; s += 16) {
    const float w = zz[s];
    const float4 v =
        *reinterpret_cast<const float4*>(src + (size_t)s * RANK + b4 * 4);
    acc.x += w * v.x; acc.y += w * v.y; acc.z += w * v.z; acc.w += w * v.w;
  }

  __shared__ float4 lds[256];
  lds[threadIdx.x] = acc;
  __syncthreads();
  if (threadIdx.x < 16) {
    float4 sum = lds[threadIdx.x];
    for (int r = 1; r < 16; ++r) {
      const float4 t = lds[r * 16 + threadIdx.x];
      sum.x += t.x; sum.y += t.y; sum.z += t.z; sum.w += t.w;
    }
    *reinterpret_cast<float4*>(
        part + ((size_t)ka * nchunk + c) * RANK + threadIdx.x * 4) = sum;
  }
}

// ---------------------------------------------------------------------------
// Kernel 2: V_last[a] = sum_s z[s] * tt_last[a, s, 0].  grid = 64 blocks.
// ---------------------------------------------------------------------------
__global__ __launch_bounds__(256) void k_vlast(
    const float* __restrict__ z, const float* __restrict__ tt_last,
    float* __restrict__ vlast) {
  const int a = blockIdx.x;
  const float* __restrict__ src = tt_last + (size_t)a * SDIM;
  float acc = 0.f;
  for (int i = threadIdx.x; i < SDIM / 4; i += 256) {
    const float4 v = *reinterpret_cast<const float4*>(src + i * 4);
    const float4 w = *reinterpret_cast<const float4*>(z + i * 4);
    acc += v.x * w.x + v.y * w.y + v.z * w.z + v.w * w.w;
  }
  __shared__ float lds[256];
  lds[threadIdx.x] = acc;
  __syncthreads();
  for (int off = 128; off > 0; off >>= 1) {
    if (threadIdx.x < off) lds[threadIdx.x] += lds[threadIdx.x + off];
    __syncthreads();
  }
  if (threadIdx.x == 0) vlast[a] = lds[0];
}

// ---------------------------------------------------------------------------
// Kernel 3 (single block): fold chunk partials into V, then compute
// u = V_0 @ V_1 @ ... @ V_5 @ V_last via right-to-left matvecs.
// ---------------------------------------------------------------------------
__global__ __launch_bounds__(256) void k_chain(
    const float* __restrict__ part, int nchunk,
    const float* __restrict__ vlast, float* __restrict__ V,
    float* __restrict__ u) {
  // Phase A: V[ka*64 + b] = sum_c part[(ka*nchunk + c)*64 + b]
  for (int e = threadIdx.x; e < NMID * RANK * RANK; e += 256) {
    const int ka = e >> 6;
    const int b = e & 63;
    float s = 0.f;
    for (int c = 0; c < nchunk; ++c)
      s += part[((size_t)ka * nchunk + c) * RANK + b];
    V[e] = s;
  }
  __threadfence();
  __syncthreads();

  // Phase B: chain of matvecs.
  __shared__ float su[RANK];
  __shared__ float snew[RANK];
  __shared__ float red[256];
  if (threadIdx.x < RANK) su[threadIdx.x] = vlast[threadIdx.x];
  __syncthreads();

  const int a = threadIdx.x >> 2;   // output row, 0..63
  const int t = threadIdx.x & 3;    // 4 threads per row
  for (int k = NMID - 1; k >= 0; --k) {
    const float* __restrict__ Vk =
        V + (size_t)k * RANK * RANK + (size_t)a * RANK;
    float s = 0.f;
    for (int b = t * 16; b < t * 16 + 16; ++b) s += Vk[b] * su[b];
    red[threadIdx.x] = s;
    __syncthreads();
    if (t == 0)
      snew[a] = red[a * 4] + red[a * 4 + 1] + red[a * 4 + 2] + red[a * 4 + 3];
    __syncthreads();
    if (threadIdx.x < RANK) su[threadIdx.x] = snew[threadIdx.x];
    __syncthreads();
  }
  if (threadIdx.x < RANK) u[threadIdx.x] = su[threadIdx.x];
}

// ---------------------------------------------------------------------------
// Kernel 4: out[s] = dot(tt_first[s, :], u).  16 lanes per row.
// ---------------------------------------------------------------------------
__global__ __launch_bounds__(256) void k_out(
    const float* __restrict__ tt_first, const float* __restrict__ u,
    float* __restrict__ out) {
  const int r = blockIdx.x * 16 + (threadIdx.x >> 4);
  const int j = threadIdx.x & 15;
  const float4 v = *reinterpret_cast<const float4*>(tt_first + (size_t)r * RANK + j * 4);
  const float4 w = *reinterpret_cast<const float4*>(u + j * 4);
  float s = v.x * w.x + v.y * w.y + v.z * w.z + v.w * w.w;
  s += __shfl_xor(s, 1, 16);
  s += __shfl_xor(s, 2, 16);
  s += __shfl_xor(s, 4, 16);
  s += __shfl_xor(s, 8, 16);
  if (j == 0) out[r] = s;
}

// ---------------------------------------------------------------------------
extern "C" void kernel_launch(void* const* d_in, const int* in_sizes, int n_in,
                              void* d_out, int out_size, void* d_ws,
                              size_t ws_size, hipStream_t stream) {
  const float* z        = (const float*)d_in[0];
  const float* tt_first = (const float*)d_in[1];
  const float* tt_mid   = (const float*)d_in[2];
  const float* tt_last  = (const float*)d_in[3];
  float* out = (float*)d_out;
  float* ws  = (float*)d_ws;

  const size_t ws_floats = ws_size / sizeof(float);
  int nchunk = 8;
  while (nchunk > 1) {
    const size_t need = (size_t)NMID * RANK * nchunk * RANK  // partials
                        + (size_t)NMID * RANK * RANK         // V
                        + RANK + RANK;                       // vlast, u
    if (need <= ws_floats) break;
    nchunk >>= 1;
  }

  float* part  = ws;
  float* V     = part + (size_t)NMID * RANK * nchunk * RANK;
  float* vlast = V + (size_t)NMID * RANK * RANK;
  float* u     = vlast + RANK;

  k_vmid_partial<<<NMID * RANK * nchunk, 256, 0, stream>>>(z, tt_mid, part, nchunk);
  k_vlast<<<RANK, 256, 0, stream>>>(z, tt_last, vlast);
  k_chain<<<1, 256, 0, stream>>>(part, nchunk, vlast, V, u);
  k_out<<<SDIM / 16, 256, 0, stream>>>(tt_first, u, out);
}

// Round 2
// 283.049 us; speedup vs baseline: 1.9686x; 1.9686x over previous
//
#include <hip/hip_runtime.h>

#define SDIM 16384
#define RANK 64
#define NMID 6
#define NCHUNK 8
#define CHUNK_LEN (SDIM / NCHUNK)   // 2048

// ---------------------------------------------------------------------------
// Kernel 1: partial V_mid.  grid = NMID*RANK*NCHUNK = 3072 blocks, 256 thr.
// Block handles one (k,a) pair and one s-chunk.  Thread layout: 8 x 32B
// column groups x 32 s-rows; each thread loads 2 float4 per iteration.
// Deterministic (fixed-order LDS reduce, no atomics).
// ---------------------------------------------------------------------------
__global__ __launch_bounds__(256) void k_vmid_partial(
    const float* __restrict__ z, const float* __restrict__ tt_mid,
    float* __restrict__ part) {
  const int idx = blockIdx.x;
  const int c  = idx & (NCHUNK - 1);
  const int ka = idx / NCHUNK;                      // k*64 + a, 0..383
  const float* __restrict__ src =
      tt_mid + ((size_t)ka * SDIM + (size_t)c * CHUNK_LEN) * RANK;
  const float* __restrict__ zz = z + (size_t)c * CHUNK_LEN;

  const int b8  = threadIdx.x & 7;                  // which 32B of the 256B row
  const int row = threadIdx.x >> 3;                 // 0..31

  float4 acc0 = {0.f, 0.f, 0.f, 0.f};
  float4 acc1 = {0.f, 0.f, 0.f, 0.f};
#pragma unroll 4
  for (int s = row; s < CHUNK_LEN; s += 32) {
    const float w = zz[s];
    const float4* p =
        reinterpret_cast<const float4*>(src + (size_t)s * RANK + b8 * 8);
    const float4 v0 = p[0];
    const float4 v1 = p[1];
    acc0.x += w * v0.x; acc0.y += w * v0.y; acc0.z += w * v0.z; acc0.w += w * v0.w;
    acc1.x += w * v1.x; acc1.y += w * v1.y; acc1.z += w * v1.z; acc1.w += w * v1.w;
  }

  // lds[row*16 + j] = float4-column j (0..15) partial for s-row group `row`
  __shared__ float4 lds[512];
  lds[threadIdx.x * 2]     = acc0;   // j = b8*2
  lds[threadIdx.x * 2 + 1] = acc1;   // j = b8*2+1
  __syncthreads();
  if (threadIdx.x < 16) {
    float4 sum = {0.f, 0.f, 0.f, 0.f};
    for (int r = 0; r < 32; ++r) {
      const float4 t = lds[r * 16 + threadIdx.x];
      sum.x += t.x; sum.y += t.y; sum.z += t.z; sum.w += t.w;
    }
    *reinterpret_cast<float4*>(
        part + ((size_t)ka * NCHUNK + c) * RANK + threadIdx.x * 4) = sum;
  }
}

// ---------------------------------------------------------------------------
// Kernel 2: V_last[a] = sum_s z[s] * tt_last[a, s, 0].  grid = 64 blocks.
// ---------------------------------------------------------------------------
__global__ __launch_bounds__(256) void k_vlast(
    const float* __restrict__ z, const float* __restrict__ tt_last,
    float* __restrict__ vlast) {
  const int a = blockIdx.x;
  const float* __restrict__ src = tt_last + (size_t)a * SDIM;
  float acc = 0.f;
  for (int i = threadIdx.x; i < SDIM / 4; i += 256) {
    const float4 v = *reinterpret_cast<const float4*>(src + i * 4);
    const float4 w = *reinterpret_cast<const float4*>(z + i * 4);
    acc += v.x * w.x + v.y * w.y + v.z * w.z + v.w * w.w;
  }
  __shared__ float lds[256];
  lds[threadIdx.x] = acc;
  __syncthreads();
  for (int off = 128; off > 0; off >>= 1) {
    if (threadIdx.x < off) lds[threadIdx.x] += lds[threadIdx.x + off];
    __syncthreads();
  }
  if (threadIdx.x == 0) vlast[a] = lds[0];
}

// ---------------------------------------------------------------------------
// Kernel 3: parallel fold of chunk partials into V.  grid = 384 blocks.
// V[ka*64 + b] = sum_c part[(ka*NCHUNK + c)*64 + b]
// ---------------------------------------------------------------------------
__global__ __launch_bounds__(64) void k_fold(
    const float* __restrict__ part, float* __restrict__ V) {
  const int ka = blockIdx.x;
  const int b  = threadIdx.x;
  float s = 0.f;
#pragma unroll
  for (int c = 0; c < NCHUNK; ++c)
    s += part[((size_t)ka * NCHUNK + c) * RANK + b];
  V[(size_t)ka * RANK + b] = s;
}

// ---------------------------------------------------------------------------
// Kernel 4 (single block, tiny): u = V_0 @ ... @ V_5 @ V_last, right-to-left.
// ---------------------------------------------------------------------------
__global__ __launch_bounds__(256) void k_chain(
    const float* __restrict__ V, const float* __restrict__ vlast,
    float* __restrict__ u) {
  __shared__ float su[RANK];
  __shared__ float snew[RANK];
  __shared__ float red[256];
  if (threadIdx.x < RANK) su[threadIdx.x] = vlast[threadIdx.x];
  __syncthreads();

  const int a = threadIdx.x >> 2;   // output row, 0..63
  const int t = threadIdx.x & 3;    // 4 threads per row
  for (int k = NMID - 1; k >= 0; --k) {
    const float* __restrict__ Vk =
        V + (size_t)k * RANK * RANK + (size_t)a * RANK + t * 16;
    float s = 0.f;
#pragma unroll
    for (int b = 0; b < 16; ++b) s += Vk[b] * su[t * 16 + b];
    red[threadIdx.x] = s;
    __syncthreads();
    if (t == 0)
      snew[a] = red[a * 4] + red[a * 4 + 1] + red[a * 4 + 2] + red[a * 4 + 3];
    __syncthreads();
    if (threadIdx.x < RANK) su[threadIdx.x] = snew[threadIdx.x];
    __syncthreads();
  }
  if (threadIdx.x < RANK) u[threadIdx.x] = su[threadIdx.x];
}

// ---------------------------------------------------------------------------
// Kernel 5: out[s] = dot(tt_first[s, :], u).  16 lanes per row.
// ---------------------------------------------------------------------------
__global__ __launch_bounds__(256) void k_out(
    const float* __restrict__ tt_first, const float* __restrict__ u,
    float* __restrict__ out) {
  const int r = blockIdx.x * 16 + (threadIdx.x >> 4);
  const int j = threadIdx.x & 15;
  const float4 v =
      *reinterpret_cast<const float4*>(tt_first + (size_t)r * RANK + j * 4);
  const float4 w = *reinterpret_cast<const float4*>(u + j * 4);
  float s = v.x * w.x + v.y * w.y + v.z * w.z + v.w * w.w;
  s += __shfl_xor(s, 1, 16);
  s += __shfl_xor(s, 2, 16);
  s += __shfl_xor(s, 4, 16);
  s += __shfl_xor(s, 8, 16);
  if (j == 0) out[r] = s;
}

// ---------------------------------------------------------------------------
extern "C" void kernel_launch(void* const* d_in, const int* in_sizes, int n_in,
                              void* d_out, int out_size, void* d_ws,
                              size_t ws_size, hipStream_t stream) {
  const float* z        = (const float*)d_in[0];
  const float* tt_first = (const float*)d_in[1];
  const float* tt_mid   = (const float*)d_in[2];
  const float* tt_last  = (const float*)d_in[3];
  float* out = (float*)d_out;
  float* ws  = (float*)d_ws;

  float* part  = ws;                                        // 196608 floats
  float* V     = part + (size_t)NMID * RANK * NCHUNK * RANK; // 24576 floats
  float* vlast = V + (size_t)NMID * RANK * RANK;            // 64
  float* u     = vlast + RANK;                              // 64

  k_vmid_partial<<<NMID * RANK * NCHUNK, 256, 0, stream>>>(z, tt_mid, part);
  k_vlast<<<RANK, 256, 0, stream>>>(z, tt_last, vlast);
  k_fold<<<NMID * RANK, 64, 0, stream>>>(part, V);
  k_chain<<<1, 256, 0, stream>>>(V, vlast, u);
  k_out<<<SDIM / 16, 256, 0, stream>>>(tt_first, u, out);
}

// Round 3
// 276.186 us; speedup vs baseline: 2.0175x; 1.0248x over previous
//
#include <hip/hip_runtime.h>

#define SDIM 16384
#define RANK 64
#define NMID 6
#define NCHUNK 8
#define CHUNK_LEN (SDIM / NCHUNK)   // 2048
#define VMID_BLOCKS (NMID * RANK * NCHUNK)  // 3072

// ---------------------------------------------------------------------------
// Kernel A: partial V_mid (blocks 0..3071) + V_last (blocks 3072..3135).
// vmid block: one (k,a) pair, one s-chunk.  8 x 32B col groups x 32 s-rows.
// Deterministic (fixed-order LDS reduce, no atomics).
// ---------------------------------------------------------------------------
__global__ __launch_bounds__(256) void k_contract(
    const float* __restrict__ z, const float* __restrict__ tt_mid,
    const float* __restrict__ tt_last, float* __restrict__ part,
    float* __restrict__ vlast) {
  if (blockIdx.x < VMID_BLOCKS) {
    const int idx = blockIdx.x;
    const int c  = idx & (NCHUNK - 1);
    const int ka = idx / NCHUNK;                    // k*64 + a, 0..383
    const float* __restrict__ src =
        tt_mid + ((size_t)ka * SDIM + (size_t)c * CHUNK_LEN) * RANK;
    const float* __restrict__ zz = z + (size_t)c * CHUNK_LEN;

    const int b8  = threadIdx.x & 7;                // which 32B of 256B row
    const int row = threadIdx.x >> 3;               // 0..31

    float4 acc0 = {0.f, 0.f, 0.f, 0.f};
    float4 acc1 = {0.f, 0.f, 0.f, 0.f};
#pragma unroll 4
    for (int s = row; s < CHUNK_LEN; s += 32) {
      const float w = zz[s];
      const float4* p =
          reinterpret_cast<const float4*>(src + (size_t)s * RANK + b8 * 8);
      const float4 v0 = p[0];
      const float4 v1 = p[1];
      acc0.x += w * v0.x; acc0.y += w * v0.y;
      acc0.z += w * v0.z; acc0.w += w * v0.w;
      acc1.x += w * v1.x; acc1.y += w * v1.y;
      acc1.z += w * v1.z; acc1.w += w * v1.w;
    }

    __shared__ float4 lds[512];
    lds[threadIdx.x * 2]     = acc0;
    lds[threadIdx.x * 2 + 1] = acc1;
    __syncthreads();
    if (threadIdx.x < 16) {
      float4 sum = {0.f, 0.f, 0.f, 0.f};
      for (int r = 0; r < 32; ++r) {
        const float4 t = lds[r * 16 + threadIdx.x];
        sum.x += t.x; sum.y += t.y; sum.z += t.z; sum.w += t.w;
      }
      *reinterpret_cast<float4*>(
          part + ((size_t)ka * NCHUNK + c) * RANK + threadIdx.x * 4) = sum;
    }
  } else {
    // V_last[a] = sum_s z[s] * tt_last[a, s, 0]
    const int a = blockIdx.x - VMID_BLOCKS;
    const float* __restrict__ src = tt_last + (size_t)a * SDIM;
    float acc = 0.f;
    for (int i = threadIdx.x; i < SDIM / 4; i += 256) {
      const float4 v = *reinterpret_cast<const float4*>(src + i * 4);
      const float4 w = *reinterpret_cast<const float4*>(z + i * 4);
      acc += v.x * w.x + v.y * w.y + v.z * w.z + v.w * w.w;
    }
    __shared__ float red[256];
    red[threadIdx.x] = acc;
    __syncthreads();
    for (int off = 128; off > 0; off >>= 1) {
      if (threadIdx.x < off) red[threadIdx.x] += red[threadIdx.x + off];
      __syncthreads();
    }
    if (threadIdx.x == 0) vlast[a] = red[0];
  }
}

// ---------------------------------------------------------------------------
// Kernel B: parallel fold of chunk partials into V.  grid = 384 blocks.
// ---------------------------------------------------------------------------
__global__ __launch_bounds__(64) void k_fold(
    const float* __restrict__ part, float* __restrict__ V) {
  const int ka = blockIdx.x;
  const int b  = threadIdx.x;
  float s = 0.f;
#pragma unroll
  for (int c = 0; c < NCHUNK; ++c)
    s += part[((size_t)ka * NCHUNK + c) * RANK + b];
  V[(size_t)ka * RANK + b] = s;
}

// ---------------------------------------------------------------------------
// Kernel C: fused chain + output.  grid = 1024 blocks, 256 threads.
// Each block redundantly computes u = V_0 @ ... @ V_5 @ V_last (L2-resident,
// identical fixed order in every block -> deterministic & consistent), then
// writes out[r] = dot(tt_first[r,:], u) for its 16 rows.
// ---------------------------------------------------------------------------
__global__ __launch_bounds__(256) void k_chain_out(
    const float* __restrict__ V, const float* __restrict__ vlast,
    const float* __restrict__ tt_first, float* __restrict__ out) {
  __shared__ float su[RANK];
  __shared__ float snew[RANK];
  __shared__ float red[256];
  if (threadIdx.x < RANK) su[threadIdx.x] = vlast[threadIdx.x];
  __syncthreads();

  const int a = threadIdx.x >> 2;   // row 0..63
  const int t = threadIdx.x & 3;    // 4 threads per row
  for (int k = NMID - 1; k >= 0; --k) {
    const float* __restrict__ Vk =
        V + (size_t)k * RANK * RANK + (size_t)a * RANK + t * 16;
    float s = 0.f;
#pragma unroll
    for (int b = 0; b < 16; ++b) s += Vk[b] * su[t * 16 + b];
    red[threadIdx.x] = s;
    __syncthreads();
    if (t == 0)
      snew[a] = red[a * 4] + red[a * 4 + 1] + red[a * 4 + 2] + red[a * 4 + 3];
    __syncthreads();
    if (threadIdx.x < RANK) su[threadIdx.x] = snew[threadIdx.x];
    __syncthreads();
  }

  // out[r] = dot(tt_first[r,:], u)   -- 16 lanes per row, u in LDS
  const int r = blockIdx.x * 16 + (threadIdx.x >> 4);
  const int j = threadIdx.x & 15;
  const float4 v =
      *reinterpret_cast<const float4*>(tt_first + (size_t)r * RANK + j * 4);
  const float4 w = *reinterpret_cast<const float4*>(su + j * 4);
  float s = v.x * w.x + v.y * w.y + v.z * w.z + v.w * w.w;
  s += __shfl_xor(s, 1, 16);
  s += __shfl_xor(s, 2, 16);
  s += __shfl_xor(s, 4, 16);
  s += __shfl_xor(s, 8, 16);
  if (j == 0) out[r] = s;
}

// ---------------------------------------------------------------------------
extern "C" void kernel_launch(void* const* d_in, const int* in_sizes, int n_in,
                              void* d_out, int out_size, void* d_ws,
                              size_t ws_size, hipStream_t stream) {
  const float* z        = (const float*)d_in[0];
  const float* tt_first = (const float*)d_in[1];
  const float* tt_mid   = (const float*)d_in[2];
  const float* tt_last  = (const float*)d_in[3];
  float* out = (float*)d_out;
  float* ws  = (float*)d_ws;

  float* part  = ws;                                         // 196608 floats
  float* V     = part + (size_t)NMID * RANK * NCHUNK * RANK; // 24576 floats
  float* vlast = V + (size_t)NMID * RANK * RANK;             // 64
  // (u no longer materialized; chain runs inside kernel C)

  k_contract<<<VMID_BLOCKS + RANK, 256, 0, stream>>>(z, tt_mid, tt_last, part, vlast);
  k_fold<<<NMID * RANK, 64, 0, stream>>>(part, V);
  k_chain_out<<<SDIM / 16, 256, 0, stream>>>(V, vlast, tt_first, out);
}